// Round 2
// baseline (102.944 us; speedup 1.0000x reference)
//
#include <hip/hip_runtime.h>

// Problem constants: B=16 batches, A=5 agents, C=512 channels, H=W=16.
#define NB 16
#define NA 5
#define NC 512
#define HW 256        // 16*16

typedef _Float16 h8 __attribute__((ext_vector_type(8)));   // 16 B = one ds_read_b128

static __device__ __forceinline__ h8 splat8(float v) {
    const _Float16 h = (_Float16)v;
    h8 r = {h, h, h, h, h, h, h, h};
    return r;
}

// Force wave-uniform values into SGPRs (trans entries depend only on block
// indices; scalar regs keep the pair-uniform weight math off the VALU).
static __device__ __forceinline__ float rfl(float v) {
    return __builtin_bit_cast(float,
        __builtin_amdgcn_readfirstlane(__builtin_bit_cast(int, v)));
}

// Block = one (batch b, channel-slab c0) slice; produces ALL 5 agents' outputs.
// The 5 agent slabs are loaded from global ONCE (f32 in regs for the exact
// residual) and staged to fp16 LDS ONCE (the previous kernel re-fetched and
// re-staged each neighbor slab 4x -- once per consuming agent).
// Grid = 16*64 = 1024 blocks = exactly 4 blocks/CU (LDS 36 KiB / 160 KiB).
__global__ __launch_bounds__(256, 4) void fafmimo_agentblock_kernel(
    const float* __restrict__ feat,   // [A*B][C][256], feat[a*B+b] = local[b][a]
    const float* __restrict__ trans,  // [B][A][A][4][4]
    const int*   __restrict__ numa,   // [B][A], use [:,0]
    float*       __restrict__ out)    // [A*B][C][256]
{
    __shared__ h8 lds_nb[NA][HW];     // 20 KiB  staged agent slabs (fp16)
    __shared__ h8 lds_rot[4][HW];     // 16 KiB  rotated intermediates (reused per i)

    const int p = threadIdx.x;
    const int x = p & 15, y = p >> 4;
    const float fx = (float)x - 7.5f;
    const float fy = (float)y - 7.5f;

    const int idx = blockIdx.x;       // 1024 items
    const int b  = idx >> 6;
    const int c0 = (idx & 63) << 3;
    const int n  = numa[b * NA];      // block-uniform

    // ---- load all 5 agent slabs (issued back-to-back for ILP) ----
    float slab[NA][8];
#pragma unroll
    for (int a = 0; a < NA; ++a) {
        const float* src = feat + ((a * NB + b) * NC + c0) * HW + p;
#pragma unroll
        for (int k = 0; k < 8; ++k) slab[a][k] = src[k * HW];
    }

    // ---- stage fp16 copies of the j<n slabs to LDS (once per item) ----
#pragma unroll
    for (int a = 0; a < NA; ++a) {
        if (a < n) {                  // block-uniform
            h8 v;
#pragma unroll
            for (int k = 0; k < 8; ++k) v[k] = (_Float16)slab[a][k];
            lds_nb[a][p] = v;
        }
    }
    __syncthreads();

    const bool anyPairs = (n > 1);    // block-uniform

#pragma unroll
    for (int i = 0; i < NA; ++i) {
        float acc[8];
#pragma unroll
        for (int k = 0; k < 8; ++k) acc[k] = slab[i][k];   // exact f32 residual

        if (anyPairs && i < n) {      // block-uniform
            // ---- Phase A: rotation bilinear at this thread's pixel ----
#pragma unroll
            for (int jj = 0; jj < 4; ++jj) {
                const int j = jj + (jj >= i);
                if (j < n) {          // block-uniform
                    const float* tw = trans + (((b * NA) + i) * NA + j) * 16;
                    const float r00 = rfl(tw[0]), r01 = rfl(tw[1]);
                    const float r10 = rfl(tw[4]), r11 = rfl(tw[5]);
                    const float bx = r00 * fx + r01 * fy + 7.5f;
                    const float by = r10 * fx + r11 * fy + 7.5f;
                    const float fbx = floorf(bx), fby = floorf(by);
                    const int ix = (int)fbx, iy = (int)fby;
                    const float wx1 = bx - fbx, wy1 = by - fby;
                    const float mx0 = (ix     >= 0 && ix     < 16) ? 1.0f - wx1 : 0.0f;
                    const float mx1 = (ix + 1 >= 0 && ix + 1 < 16) ? wx1 : 0.0f;
                    const float my0 = (iy     >= 0 && iy     < 16) ? 1.0f - wy1 : 0.0f;
                    const float my1 = (iy + 1 >= 0 && iy + 1 < 16) ? wy1 : 0.0f;
                    const int cx0 = min(max(ix, 0), 15), cx1 = min(max(ix + 1, 0), 15);
                    const int cy0 = min(max(iy, 0), 15), cy1 = min(max(iy + 1, 0), 15);
                    const h8 v00 = lds_nb[j][cy0 * 16 + cx0];
                    const h8 v01 = lds_nb[j][cy0 * 16 + cx1];
                    const h8 v10 = lds_nb[j][cy1 * 16 + cx0];
                    const h8 v11 = lds_nb[j][cy1 * 16 + cx1];
                    lds_rot[jj][p] =
                          v00 * splat8(mx0 * my0) + v01 * splat8(mx1 * my0)
                        + v10 * splat8(mx0 * my1) + v11 * splat8(mx1 * my1);
                }
            }
            __syncthreads();

            // ---- Phase B: pair-uniform 2x2 translation stencil ----
#pragma unroll
            for (int jj = 0; jj < 4; ++jj) {
                const int j = jj + (jj >= i);
                if (j < n) {          // block-uniform
                    const float* tw = trans + (((b * NA) + i) * NA + j) * 16;
                    const float dx =  0.25f * rfl(tw[3]);
                    const float dy = -0.25f * rfl(tw[7]);
                    const float fdx = floorf(dx), fdy = floorf(dy);
                    const float tx1 = dx - fdx, tx0 = 1.0f - tx1;
                    const float ty1 = dy - fdy, ty0 = 1.0f - ty1;
                    const int ox = x + (int)fdx;
                    const int oy = y + (int)fdy;
                    const bool inx0 = (ox     >= 0) && (ox     < 16);
                    const bool inx1 = (ox + 1 >= 0) && (ox + 1 < 16);
                    const bool iny0 = (oy     >= 0) && (oy     < 16);
                    const bool iny1 = (oy + 1 >= 0) && (oy + 1 < 16);
                    const float w00 = (inx0 && iny0) ? tx0 * ty0 : 0.0f;
                    const float w10 = (inx1 && iny0) ? tx1 * ty0 : 0.0f;
                    const float w01 = (inx0 && iny1) ? tx0 * ty1 : 0.0f;
                    const float w11 = (inx1 && iny1) ? tx1 * ty1 : 0.0f;
                    const int cx0 = min(max(ox, 0), 15), cx1 = min(max(ox + 1, 0), 15);
                    const int cy0 = min(max(oy, 0), 15), cy1 = min(max(oy + 1, 0), 15);
                    const h8 t00 = lds_rot[jj][cy0 * 16 + cx0];
                    const h8 t01 = lds_rot[jj][cy0 * 16 + cx1];
                    const h8 t10 = lds_rot[jj][cy1 * 16 + cx0];
                    const h8 t11 = lds_rot[jj][cy1 * 16 + cx1];
                    const h8 s = t00 * splat8(w00) + t01 * splat8(w10)
                               + t10 * splat8(w01) + t11 * splat8(w11);
#pragma unroll
                    for (int k = 0; k < 8; ++k) acc[k] += (float)s[k];  // f32 accum
                }
            }
            __syncthreads();          // lds_rot reused by next i's Phase A
        }

        float* dst = out + ((i * NB + b) * NC + c0) * HW + p;
#pragma unroll
        for (int k = 0; k < 8; ++k) dst[k * HW] = acc[k];
    }
}

extern "C" void kernel_launch(void* const* d_in, const int* in_sizes, int n_in,
                              void* d_out, int out_size, void* d_ws, size_t ws_size,
                              hipStream_t stream) {
    const float* feat  = (const float*)d_in[0];
    const float* trans = (const float*)d_in[1];
    const int*   numa  = (const int*)d_in[2];
    float* out = (float*)d_out;

    fafmimo_agentblock_kernel<<<dim3(NB * 64), dim3(256), 0, stream>>>(
        feat, trans, numa, out);
}